// Round 5
// baseline (444.698 us; speedup 1.0000x reference)
//
#include <hip/hip_runtime.h>

#define D 64

__device__ __forceinline__ float bcast(float v, int lane_lit) {
    return __int_as_float(__builtin_amdgcn_readlane(__float_as_int(v), lane_lit));
}

// ================= CSR build: counting sort by key = dst*nch + chunk(src) ===
__global__ void hist_kernel(const int* __restrict__ dst, const int* __restrict__ src,
                            int* __restrict__ deg, int E, int nch, unsigned csize) {
    int i = blockIdx.x * blockDim.x + threadIdx.x;
    int base = i * 8;
    if (base + 8 <= E) {
        int4 d0 = *reinterpret_cast<const int4*>(dst + base);
        int4 d1 = *reinterpret_cast<const int4*>(dst + base + 4);
        int4 s0 = *reinterpret_cast<const int4*>(src + base);
        int4 s1 = *reinterpret_cast<const int4*>(src + base + 4);
        int k0 = d0.x * nch + (int)((unsigned)s0.x / csize);
        int k1 = d0.y * nch + (int)((unsigned)s0.y / csize);
        int k2 = d0.z * nch + (int)((unsigned)s0.z / csize);
        int k3 = d0.w * nch + (int)((unsigned)s0.w / csize);
        int k4 = d1.x * nch + (int)((unsigned)s1.x / csize);
        int k5 = d1.y * nch + (int)((unsigned)s1.y / csize);
        int k6 = d1.z * nch + (int)((unsigned)s1.z / csize);
        int k7 = d1.w * nch + (int)((unsigned)s1.w / csize);
        atomicAdd(&deg[k0], 1); atomicAdd(&deg[k1], 1);
        atomicAdd(&deg[k2], 1); atomicAdd(&deg[k3], 1);
        atomicAdd(&deg[k4], 1); atomicAdd(&deg[k5], 1);
        atomicAdd(&deg[k6], 1); atomicAdd(&deg[k7], 1);
    } else {
        for (int e = base; e < E; ++e) {
            int k = dst[e] * nch + (int)((unsigned)src[e] / csize);
            atomicAdd(&deg[k], 1);
        }
    }
}

__global__ void scan_k1(const int* __restrict__ deg, int* __restrict__ bsum, int n) {
    __shared__ int sh[256];
    int t = threadIdx.x;
    int g = blockIdx.x * 256 + t;
    int v = (g < n) ? deg[g] : 0;
    sh[t] = v;
    __syncthreads();
    for (int off = 1; off < 256; off <<= 1) {
        int u = (t >= off) ? sh[t - off] : 0;
        __syncthreads();
        sh[t] += u;
        __syncthreads();
    }
    if (t == 255) bsum[blockIdx.x] = sh[255];
}

__global__ void scan_k2(const int* __restrict__ bsum, int* __restrict__ boff, int nb) {
    __shared__ int sh[1024];
    int t = threadIdx.x;
    int v = (t < nb) ? bsum[t] : 0;
    sh[t] = v;
    __syncthreads();
    for (int off = 1; off < 1024; off <<= 1) {
        int u = (t >= off) ? sh[t - off] : 0;
        __syncthreads();
        sh[t] += u;
        __syncthreads();
    }
    if (t < nb) boff[t] = sh[t] - v;
}

// cursor may alias deg: each thread reads deg[g] before writing cursor[g].
__global__ void scan_k3(const int* __restrict__ deg, const int* __restrict__ boff,
                        int* __restrict__ row_ptr, int* __restrict__ cursor, int n) {
    __shared__ int sh[256];
    int t = threadIdx.x;
    int g = blockIdx.x * 256 + t;
    int v = (g < n) ? deg[g] : 0;
    sh[t] = v;
    __syncthreads();
    for (int off = 1; off < 256; off <<= 1) {
        int u = (t >= off) ? sh[t - off] : 0;
        __syncthreads();
        sh[t] += u;
        __syncthreads();
    }
    if (g < n) {
        int excl = sh[t] - v + boff[blockIdx.x];
        row_ptr[g] = excl;
        cursor[g] = excl;
        if (g == n - 1) row_ptr[n] = excl + v;
    }
}

__global__ void perm_kernel(const int* __restrict__ src, const int* __restrict__ dst,
                            int* __restrict__ cursor, int* __restrict__ sorted_src,
                            int E, int nch, unsigned csize) {
    int i = blockIdx.x * blockDim.x + threadIdx.x;
    int base = i * 8;
    if (base + 8 <= E) {
        int4 d0 = *reinterpret_cast<const int4*>(dst + base);
        int4 d1 = *reinterpret_cast<const int4*>(dst + base + 4);
        int4 s0 = *reinterpret_cast<const int4*>(src + base);
        int4 s1 = *reinterpret_cast<const int4*>(src + base + 4);
        int k0 = d0.x * nch + (int)((unsigned)s0.x / csize);
        int k1 = d0.y * nch + (int)((unsigned)s0.y / csize);
        int k2 = d0.z * nch + (int)((unsigned)s0.z / csize);
        int k3 = d0.w * nch + (int)((unsigned)s0.w / csize);
        int k4 = d1.x * nch + (int)((unsigned)s1.x / csize);
        int k5 = d1.y * nch + (int)((unsigned)s1.y / csize);
        int k6 = d1.z * nch + (int)((unsigned)s1.z / csize);
        int k7 = d1.w * nch + (int)((unsigned)s1.w / csize);
        // 8 independent atomic chains in flight
        int p0 = atomicAdd(&cursor[k0], 1);
        int p1 = atomicAdd(&cursor[k1], 1);
        int p2 = atomicAdd(&cursor[k2], 1);
        int p3 = atomicAdd(&cursor[k3], 1);
        int p4 = atomicAdd(&cursor[k4], 1);
        int p5 = atomicAdd(&cursor[k5], 1);
        int p6 = atomicAdd(&cursor[k6], 1);
        int p7 = atomicAdd(&cursor[k7], 1);
        __builtin_nontemporal_store(s0.x, &sorted_src[p0]);
        __builtin_nontemporal_store(s0.y, &sorted_src[p1]);
        __builtin_nontemporal_store(s0.z, &sorted_src[p2]);
        __builtin_nontemporal_store(s0.w, &sorted_src[p3]);
        __builtin_nontemporal_store(s1.x, &sorted_src[p4]);
        __builtin_nontemporal_store(s1.y, &sorted_src[p5]);
        __builtin_nontemporal_store(s1.z, &sorted_src[p6]);
        __builtin_nontemporal_store(s1.w, &sorted_src[p7]);
    } else {
        for (int e = base; e < E; ++e) {
            int k = dst[e] * nch + (int)((unsigned)src[e] / csize);
            int p = atomicAdd(&cursor[k], 1);
            __builtin_nontemporal_store(src[e], &sorted_src[p]);
        }
    }
}

// ====== gather (per src-chunk): agg[n] += sum_{e in row (n,c)} xin[src_e] ===
// Wave = 4 groups x 16 lanes; one float4 load instruction covers 4 edges (1KB).
// Cross-group combine via 2 shfl_xor butterflies. c>0 accumulates into agg.
__global__ void __launch_bounds__(256)
gather_chunk(const float4* __restrict__ xin4,
             const int* __restrict__ row_ptr,
             const int* __restrict__ sorted_src,
             float4* __restrict__ agg4,
             int n_nodes, int nch, int c, int accumulate) {
    int wid = blockIdx.x * (blockDim.x >> 6) + (threadIdx.x >> 6);
    if (wid >= n_nodes) return;
    int lane = threadIdx.x & 63;
    int g = lane >> 4;
    int j = lane & 15;

    int row = wid * nch + c;
    int beg = row_ptr[row];
    int end = row_ptr[row + 1];

    float ax = 0.f, ay = 0.f, az = 0.f, aw = 0.f;
    for (int e = beg; e < end; e += 8) {
        int e0 = e + g;
        int e1 = e + 4 + g;
        if (e0 < end) {
            int s = sorted_src[e0];
            float4 v = xin4[((size_t)(unsigned)s << 4) + j];
            ax += v.x; ay += v.y; az += v.z; aw += v.w;
        }
        if (e1 < end) {
            int s = sorted_src[e1];
            float4 v = xin4[((size_t)(unsigned)s << 4) + j];
            ax += v.x; ay += v.y; az += v.z; aw += v.w;
        }
    }
    // combine the 4 groups (butterfly over lane bits 4,5)
    ax += __shfl_xor(ax, 16); ay += __shfl_xor(ay, 16);
    az += __shfl_xor(az, 16); aw += __shfl_xor(aw, 16);
    ax += __shfl_xor(ax, 32); ay += __shfl_xor(ay, 32);
    az += __shfl_xor(az, 32); aw += __shfl_xor(aw, 32);

    if (g == 0) {
        size_t o = ((size_t)(unsigned)wid << 4) + j;
        float4 r;
        r.x = ax; r.y = ay; r.z = az; r.w = aw;
        if (accumulate) {
            float4 t = agg4[o];
            r.x += t.x; r.y += t.y; r.z += t.z; r.w += t.w;
        }
        agg4[o] = r;
    }
}

// ============ dense: out[n] = xin[n]@Ws + agg[n]@Wm + b (+ReLU) =============
__global__ void __launch_bounds__(256)
dense_kernel2(const float* __restrict__ xin,
              const float* __restrict__ agg,
              const float* __restrict__ Wself,
              const float* __restrict__ Wmsg,
              const float* __restrict__ bias,
              float* __restrict__ xout,
              int n_nodes, int do_relu) {
    int lane = threadIdx.x & 63;
    int wave = threadIdx.x >> 6;
    int wpb = blockDim.x >> 6;

    float Wsc[D], Wmc[D];
#pragma unroll
    for (int k = 0; k < D; ++k) {
        Wsc[k] = Wself[k * D + lane];
        Wmc[k] = Wmsg[k * D + lane];
    }
    float bj = bias[lane];

    for (int n = blockIdx.x * wpb + wave; n < n_nodes; n += gridDim.x * wpb) {
        float xv = xin[((unsigned)n << 6) + lane];
        float av = agg[((unsigned)n << 6) + lane];

        float acc0 = bj, acc1 = 0.f, acc2 = 0.f, acc3 = 0.f;
#pragma unroll
        for (int k = 0; k < D; k += 4) {
            acc0 = fmaf(bcast(xv, k + 0), Wsc[k + 0], acc0);
            acc1 = fmaf(bcast(xv, k + 1), Wsc[k + 1], acc1);
            acc2 = fmaf(bcast(xv, k + 2), Wsc[k + 2], acc2);
            acc3 = fmaf(bcast(xv, k + 3), Wsc[k + 3], acc3);
            acc0 = fmaf(bcast(av, k + 0), Wmc[k + 0], acc0);
            acc1 = fmaf(bcast(av, k + 1), Wmc[k + 1], acc1);
            acc2 = fmaf(bcast(av, k + 2), Wmc[k + 2], acc2);
            acc3 = fmaf(bcast(av, k + 3), Wmc[k + 3], acc3);
        }
        float acc = (acc0 + acc1) + (acc2 + acc3);
        if (do_relu) acc = fmaxf(acc, 0.f);
        xout[((unsigned)n << 6) + lane] = acc;
    }
}

// ================= fallback (atomic path) ===================================
__global__ void scatter_kernel(const float* __restrict__ x,
                               const int* __restrict__ src,
                               const int* __restrict__ dst,
                               float* __restrict__ agg, int n_edges) {
    int e = blockIdx.x * (blockDim.x >> 6) + (threadIdx.x >> 6);
    int lane = threadIdx.x & 63;
    if (e >= n_edges) return;
    float v = x[(size_t)src[e] * D + lane];
    unsafeAtomicAdd(&agg[(size_t)dst[e] * D + lane], v);
}

__global__ void dense_kernel(const float* __restrict__ xin,
                             const float* __restrict__ agg,
                             const float* __restrict__ Wself,
                             const float* __restrict__ Wmsg,
                             const float* __restrict__ bias,
                             float* __restrict__ xout,
                             int n_nodes, int do_relu) {
    __shared__ float Ws[D * D];
    __shared__ float Wm[D * D];
    for (int i = threadIdx.x; i < D * D; i += blockDim.x) {
        Ws[i] = Wself[i];
        Wm[i] = Wmsg[i];
    }
    __syncthreads();
    int lane = threadIdx.x & 63;
    int wave = threadIdx.x >> 6;
    int wpb = blockDim.x >> 6;
    float bj = bias[lane];
    for (int n = blockIdx.x * wpb + wave; n < n_nodes; n += gridDim.x * wpb) {
        float xv = xin[(size_t)n * D + lane];
        float av = agg[(size_t)n * D + lane];
        float acc = bj;
#pragma unroll
        for (int k = 0; k < D; ++k) {
            acc += __shfl(xv, k, 64) * Ws[k * D + lane]
                 + __shfl(av, k, 64) * Wm[k * D + lane];
        }
        if (do_relu) acc = fmaxf(acc, 0.f);
        xout[(size_t)n * D + lane] = acc;
    }
}

// ============================================================================
static size_t ws_need(int N, int E, int nch) {
    size_t nk = (size_t)N * nch;
    size_t nbb = (nk + 255) / 256;
    return (size_t)N * D * 4            // A ping buffer
         + (size_t)E * 4                // sorted_src
         + (nk + 1) * 4                 // row_ptr
         + nk * 4                       // deg (aliased as cursor)
         + nbb * 4 * 2 + 256;           // bsum + boff + slack
}

extern "C" void kernel_launch(void* const* d_in, const int* in_sizes, int n_in,
                              void* d_out, int out_size, void* d_ws, size_t ws_size,
                              hipStream_t stream) {
    const float* x0    = (const float*)d_in[0];
    const int*   ei    = (const int*)d_in[1];
    const float* Wmsg  = (const float*)d_in[2];
    const float* Wself = (const float*)d_in[3];
    const float* bias  = (const float*)d_in[4];
    float* out = (float*)d_out;

    const int N = in_sizes[0] / D;         // 50000
    const int E = in_sizes[1] / 2;         // 800000
    const int n_layers = in_sizes[4] / D;  // 3

    const int* src = ei;
    const int* dst = ei + E;
    const size_t NB = (size_t)N * D * sizeof(float);

    // pick chunk count: 4 (src slice ~3.2MB, fits one XCD L2) if ws allows
    int NCH = 4;
    if (ws_size < ws_need(N, E, NCH) || (size_t)N * NCH > 256u * 1024) NCH = 1;

    if (ws_size >= ws_need(N, E, NCH)) {
        const int NK = N * NCH;
        const int NBB = (NK + 255) / 256;
        const unsigned csize = (unsigned)((N + NCH - 1) / NCH);

        char* p = (char*)d_ws;
        float* A          = (float*)p;  p += NB;
        int*   sorted_src = (int*)p;    p += (size_t)E * 4;
        int*   row_ptr    = (int*)p;    p += (size_t)(NK + 1) * 4;
        int*   deg        = (int*)p;    p += (size_t)NK * 4;     // also cursor
        int*   bsum       = (int*)p;    p += (size_t)NBB * 4;
        int*   boff       = (int*)p;
        int*   cursor     = deg;

        hipMemsetAsync(deg, 0, (size_t)NK * 4, stream);
        {
            int threads = 256;
            int nthreads = (E + 7) / 8;
            int blocks = (nthreads + threads - 1) / threads;
            hist_kernel<<<blocks, threads, 0, stream>>>(dst, src, deg, E, NCH, csize);
            scan_k1<<<NBB, 256, 0, stream>>>(deg, bsum, NK);
            scan_k2<<<1, 1024, 0, stream>>>(bsum, boff, NBB);
            scan_k3<<<NBB, 256, 0, stream>>>(deg, boff, row_ptr, cursor, NK);
            perm_kernel<<<blocks, threads, 0, stream>>>(src, dst, cursor, sorted_src,
                                                        E, NCH, csize);
        }

        const int WPB = 4;
        const int gather_blocks = (N + WPB - 1) / WPB;
        const int dense_blocks = 1024;

        const float* cur = x0;
        for (int layer = 0; layer < n_layers; ++layer) {
            float* aggbuf = (layer % 2 == 0) ? A : out;
            float* tgt = (layer == n_layers - 1) ? out : aggbuf;
            for (int c = 0; c < NCH; ++c) {
                gather_chunk<<<gather_blocks, WPB * 64, 0, stream>>>(
                    (const float4*)cur, row_ptr, sorted_src,
                    (float4*)aggbuf, N, NCH, c, c > 0 ? 1 : 0);
            }
            dense_kernel2<<<dense_blocks, 256, 0, stream>>>(
                cur, aggbuf,
                Wself + (size_t)layer * D * D,
                Wmsg  + (size_t)layer * D * D,
                bias  + (size_t)layer * D,
                tgt, N, (layer < n_layers - 1) ? 1 : 0);
            cur = tgt;
        }
    } else {
        float* agg = (float*)d_ws;
        const int EPB = 256 / 64;
        const int scatter_blocks = (E + EPB - 1) / EPB;
        for (int layer = 0; layer < n_layers; ++layer) {
            hipMemsetAsync(agg, 0, NB, stream);
            const float* xin = (layer == 0) ? x0 : out;
            scatter_kernel<<<scatter_blocks, 256, 0, stream>>>(xin, src, dst, agg, E);
            dense_kernel<<<1024, 256, 0, stream>>>(
                xin, agg,
                Wself + (size_t)layer * D * D,
                Wmsg  + (size_t)layer * D * D,
                bias  + (size_t)layer * D,
                out, N, (layer < n_layers - 1) ? 1 : 0);
        }
    }
}

// Round 6
// 339.756 us; speedup vs baseline: 1.3089x; 1.3089x over previous
//
#include <hip/hip_runtime.h>

#define D 64

// ---- bf16 helpers (RNE), raw ushort storage ------------------------------
__device__ __forceinline__ unsigned short f2bf(float f) {
    unsigned u = __float_as_uint(f);
    unsigned r = (u + 0x7FFFu + ((u >> 16) & 1u)) >> 16;
    return (unsigned short)r;
}
__device__ __forceinline__ float bf2f(unsigned short h) {
    return __uint_as_float((unsigned)h << 16);
}
__device__ __forceinline__ float bcast(float v, int lane_lit) {
    return __int_as_float(__builtin_amdgcn_readlane(__float_as_int(v), lane_lit));
}

// ================= CSR build: hist captures per-edge rank ===================
__global__ void hist_rank_kernel(const int* __restrict__ dst, int* __restrict__ deg,
                                 int* __restrict__ rank, int E) {
    int i = blockIdx.x * blockDim.x + threadIdx.x;
    int base = i * 8;
    if (base + 8 <= E) {
        int4 d0 = *reinterpret_cast<const int4*>(dst + base);
        int4 d1 = *reinterpret_cast<const int4*>(dst + base + 4);
        int4 r0, r1;                       // 8 independent atomic chains
        r0.x = atomicAdd(&deg[d0.x], 1);
        r0.y = atomicAdd(&deg[d0.y], 1);
        r0.z = atomicAdd(&deg[d0.z], 1);
        r0.w = atomicAdd(&deg[d0.w], 1);
        r1.x = atomicAdd(&deg[d1.x], 1);
        r1.y = atomicAdd(&deg[d1.y], 1);
        r1.z = atomicAdd(&deg[d1.z], 1);
        r1.w = atomicAdd(&deg[d1.w], 1);
        *reinterpret_cast<int4*>(rank + base) = r0;       // contiguous stream
        *reinterpret_cast<int4*>(rank + base + 4) = r1;
    } else {
        for (int e = base; e < E; ++e) rank[e] = atomicAdd(&deg[dst[e]], 1);
    }
}

__global__ void scan_k1(const int* __restrict__ deg, int* __restrict__ bsum, int n) {
    __shared__ int sh[256];
    int t = threadIdx.x;
    int g = blockIdx.x * 256 + t;
    int v = (g < n) ? deg[g] : 0;
    sh[t] = v;
    __syncthreads();
    for (int off = 1; off < 256; off <<= 1) {
        int u = (t >= off) ? sh[t - off] : 0;
        __syncthreads();
        sh[t] += u;
        __syncthreads();
    }
    if (t == 255) bsum[blockIdx.x] = sh[255];
}

__global__ void scan_k2(const int* __restrict__ bsum, int* __restrict__ boff, int nb) {
    __shared__ int sh[1024];
    int t = threadIdx.x;
    int v = (t < nb) ? bsum[t] : 0;
    sh[t] = v;
    __syncthreads();
    for (int off = 1; off < 1024; off <<= 1) {
        int u = (t >= off) ? sh[t - off] : 0;
        __syncthreads();
        sh[t] += u;
        __syncthreads();
    }
    if (t < nb) boff[t] = sh[t] - v;
}

__global__ void scan_k3(const int* __restrict__ deg, const int* __restrict__ boff,
                        int* __restrict__ row_ptr, int n) {
    __shared__ int sh[256];
    int t = threadIdx.x;
    int g = blockIdx.x * 256 + t;
    int v = (g < n) ? deg[g] : 0;
    sh[t] = v;
    __syncthreads();
    for (int off = 1; off < 256; off <<= 1) {
        int u = (t >= off) ? sh[t - off] : 0;
        __syncthreads();
        sh[t] += u;
        __syncthreads();
    }
    if (g < n) {
        int excl = sh[t] - v + boff[blockIdx.x];
        row_ptr[g] = excl;
        if (g == n - 1) row_ptr[n] = excl + v;
    }
}

// atomic-free permutation: pos = row_ptr[dst] + rank
__global__ void perm_rank_kernel(const int* __restrict__ src, const int* __restrict__ dst,
                                 const int* __restrict__ rank, const int* __restrict__ row_ptr,
                                 int* __restrict__ sorted_src, int E) {
    int i = blockIdx.x * blockDim.x + threadIdx.x;
    int base = i * 8;
    if (base + 8 <= E) {
        int4 d0 = *reinterpret_cast<const int4*>(dst + base);
        int4 d1 = *reinterpret_cast<const int4*>(dst + base + 4);
        int4 s0 = *reinterpret_cast<const int4*>(src + base);
        int4 s1 = *reinterpret_cast<const int4*>(src + base + 4);
        int4 r0 = *reinterpret_cast<const int4*>(rank + base);
        int4 r1 = *reinterpret_cast<const int4*>(rank + base + 4);
        int p0 = row_ptr[d0.x] + r0.x;
        int p1 = row_ptr[d0.y] + r0.y;
        int p2 = row_ptr[d0.z] + r0.z;
        int p3 = row_ptr[d0.w] + r0.w;
        int p4 = row_ptr[d1.x] + r1.x;
        int p5 = row_ptr[d1.y] + r1.y;
        int p6 = row_ptr[d1.z] + r1.z;
        int p7 = row_ptr[d1.w] + r1.w;
        __builtin_nontemporal_store(s0.x, &sorted_src[p0]);
        __builtin_nontemporal_store(s0.y, &sorted_src[p1]);
        __builtin_nontemporal_store(s0.z, &sorted_src[p2]);
        __builtin_nontemporal_store(s0.w, &sorted_src[p3]);
        __builtin_nontemporal_store(s1.x, &sorted_src[p4]);
        __builtin_nontemporal_store(s1.y, &sorted_src[p5]);
        __builtin_nontemporal_store(s1.z, &sorted_src[p6]);
        __builtin_nontemporal_store(s1.w, &sorted_src[p7]);
    } else {
        for (int e = base; e < E; ++e)
            sorted_src[row_ptr[dst[e]] + rank[e]] = src[e];
    }
}

// ================= x (fp32) -> Xb (bf16) ====================================
__global__ void convert_kernel(const float* __restrict__ x, unsigned short* __restrict__ xb,
                               int total) {
    int i = blockIdx.x * blockDim.x + threadIdx.x;
    int base = i * 4;
    if (base + 4 <= total) {
        float4 v = *reinterpret_cast<const float4*>(x + base);
        ushort4 o;
        o.x = f2bf(v.x); o.y = f2bf(v.y); o.z = f2bf(v.z); o.w = f2bf(v.w);
        *reinterpret_cast<ushort4*>(xb + base) = o;
    } else {
        for (int k = base; k < total; ++k) xb[k] = f2bf(x[k]);
    }
}

// ====== gather: agg[n] = sum_{e in row n} bf2f(xb[src_e]) (fp32 accum) ======
__global__ void __launch_bounds__(256)
gather_bf16(const unsigned short* __restrict__ xb,
            const int* __restrict__ row_ptr,
            const int* __restrict__ sorted_src,
            float* __restrict__ agg, int n_nodes) {
    int lane = threadIdx.x & 63;
    int n = blockIdx.x * (blockDim.x >> 6) + (threadIdx.x >> 6);
    if (n >= n_nodes) return;

    int beg = row_ptr[n];
    int end = row_ptr[n + 1];

    float a0 = 0.f, a1 = 0.f, a2 = 0.f, a3 = 0.f;
    int e = beg;
    for (; e + 16 <= end; e += 16) {
        int s[16];
#pragma unroll
        for (int i = 0; i < 16; ++i) s[i] = sorted_src[e + i];
        float v[16];
#pragma unroll
        for (int i = 0; i < 16; ++i) v[i] = bf2f(xb[((unsigned)s[i] << 6) + lane]);
        a0 += ((v[0] + v[1]) + (v[2] + v[3]));
        a1 += ((v[4] + v[5]) + (v[6] + v[7]));
        a2 += ((v[8] + v[9]) + (v[10] + v[11]));
        a3 += ((v[12] + v[13]) + (v[14] + v[15]));
    }
    for (; e + 4 <= end; e += 4) {
        int s0 = sorted_src[e + 0], s1 = sorted_src[e + 1];
        int s2 = sorted_src[e + 2], s3 = sorted_src[e + 3];
        a0 += bf2f(xb[((unsigned)s0 << 6) + lane]);
        a1 += bf2f(xb[((unsigned)s1 << 6) + lane]);
        a2 += bf2f(xb[((unsigned)s2 << 6) + lane]);
        a3 += bf2f(xb[((unsigned)s3 << 6) + lane]);
    }
    for (; e < end; ++e) a0 += bf2f(xb[((unsigned)sorted_src[e] << 6) + lane]);

    agg[((unsigned)n << 6) + lane] = (a0 + a1) + (a2 + a3);
}

// ====== dense: y[n] = xb[n]@Ws + agg[n]@Wm + b; mode: bf16+relu or fp32 =====
// In-place safe (each wave reads only its own row before writing it).
__global__ void __launch_bounds__(256)
dense_bf16(const unsigned short* __restrict__ xb,
           const float* __restrict__ agg,
           const float* __restrict__ Wself,
           const float* __restrict__ Wmsg,
           const float* __restrict__ bias,
           float* __restrict__ out_f32,            // used when last==1
           unsigned short* __restrict__ out_bf16,  // used when last==0 (+relu)
           int n_nodes, int last) {
    int lane = threadIdx.x & 63;
    int wave = threadIdx.x >> 6;
    int wpb = blockDim.x >> 6;

    float Wsc[D], Wmc[D];
#pragma unroll
    for (int k = 0; k < D; ++k) {
        Wsc[k] = Wself[k * D + lane];
        Wmc[k] = Wmsg[k * D + lane];
    }
    float bj = bias[lane];

    for (int n = blockIdx.x * wpb + wave; n < n_nodes; n += gridDim.x * wpb) {
        float xv = bf2f(xb[((unsigned)n << 6) + lane]);
        float av = agg[((unsigned)n << 6) + lane];

        float acc0 = bj, acc1 = 0.f, acc2 = 0.f, acc3 = 0.f;
#pragma unroll
        for (int k = 0; k < D; k += 4) {
            acc0 = fmaf(bcast(xv, k + 0), Wsc[k + 0], acc0);
            acc1 = fmaf(bcast(xv, k + 1), Wsc[k + 1], acc1);
            acc2 = fmaf(bcast(xv, k + 2), Wsc[k + 2], acc2);
            acc3 = fmaf(bcast(xv, k + 3), Wsc[k + 3], acc3);
            acc0 = fmaf(bcast(av, k + 0), Wmc[k + 0], acc0);
            acc1 = fmaf(bcast(av, k + 1), Wmc[k + 1], acc1);
            acc2 = fmaf(bcast(av, k + 2), Wmc[k + 2], acc2);
            acc3 = fmaf(bcast(av, k + 3), Wmc[k + 3], acc3);
        }
        float acc = (acc0 + acc1) + (acc2 + acc3);
        if (last) {
            out_f32[((unsigned)n << 6) + lane] = acc;
        } else {
            out_bf16[((unsigned)n << 6) + lane] = f2bf(fmaxf(acc, 0.f));
        }
    }
}

// ================= fallback (atomic path, fp32-exact) =======================
__global__ void scatter_kernel(const float* __restrict__ x,
                               const int* __restrict__ src,
                               const int* __restrict__ dst,
                               float* __restrict__ agg, int n_edges) {
    int e = blockIdx.x * (blockDim.x >> 6) + (threadIdx.x >> 6);
    int lane = threadIdx.x & 63;
    if (e >= n_edges) return;
    float v = x[(size_t)src[e] * D + lane];
    unsafeAtomicAdd(&agg[(size_t)dst[e] * D + lane], v);
}

__global__ void dense_kernel(const float* __restrict__ xin,
                             const float* __restrict__ agg,
                             const float* __restrict__ Wself,
                             const float* __restrict__ Wmsg,
                             const float* __restrict__ bias,
                             float* __restrict__ xout,
                             int n_nodes, int do_relu) {
    __shared__ float Ws[D * D];
    __shared__ float Wm[D * D];
    for (int i = threadIdx.x; i < D * D; i += blockDim.x) {
        Ws[i] = Wself[i];
        Wm[i] = Wmsg[i];
    }
    __syncthreads();
    int lane = threadIdx.x & 63;
    int wave = threadIdx.x >> 6;
    int wpb = blockDim.x >> 6;
    float bj = bias[lane];
    for (int n = blockIdx.x * wpb + wave; n < n_nodes; n += gridDim.x * wpb) {
        float xv = xin[(size_t)n * D + lane];
        float av = agg[(size_t)n * D + lane];
        float acc = bj;
#pragma unroll
        for (int k = 0; k < D; ++k) {
            acc += __shfl(xv, k, 64) * Ws[k * D + lane]
                 + __shfl(av, k, 64) * Wm[k * D + lane];
        }
        if (do_relu) acc = fmaxf(acc, 0.f);
        xout[(size_t)n * D + lane] = acc;
    }
}

// ============================================================================
extern "C" void kernel_launch(void* const* d_in, const int* in_sizes, int n_in,
                              void* d_out, int out_size, void* d_ws, size_t ws_size,
                              hipStream_t stream) {
    const float* x0    = (const float*)d_in[0];
    const int*   ei    = (const int*)d_in[1];
    const float* Wmsg  = (const float*)d_in[2];
    const float* Wself = (const float*)d_in[3];
    const float* bias  = (const float*)d_in[4];
    float* out = (float*)d_out;

    const int N = in_sizes[0] / D;         // 50000
    const int E = in_sizes[1] / 2;         // 800000
    const int n_layers = in_sizes[4] / D;  // 3

    const int* src = ei;
    const int* dst = ei + E;
    const size_t NB = (size_t)N * D * sizeof(float);

    const int NBB = (N + 255) / 256;
    const size_t need = (size_t)N * D * 2          // Xb (bf16 activations)
                      + (size_t)E * 4              // sorted_src
                      + (size_t)E * 4              // rank
                      + (size_t)(N + 1) * 4        // row_ptr
                      + (size_t)N * 4              // deg
                      + (size_t)NBB * 4 * 2 + 256; // bsum + boff + slack

    if (ws_size >= need && NBB <= 1024) {
        char* p = (char*)d_ws;
        unsigned short* Xb = (unsigned short*)p;  p += (size_t)N * D * 2;
        int* sorted_src    = (int*)p;             p += (size_t)E * 4;
        int* rank          = (int*)p;             p += (size_t)E * 4;
        int* row_ptr       = (int*)p;             p += (size_t)(N + 1) * 4;
        int* deg           = (int*)p;             p += (size_t)N * 4;
        int* bsum          = (int*)p;             p += (size_t)NBB * 4;
        int* boff          = (int*)p;

        hipMemsetAsync(deg, 0, (size_t)N * 4, stream);
        {
            int threads = 256;
            int nthr = (E + 7) / 8;
            int blocks = (nthr + threads - 1) / threads;
            hist_rank_kernel<<<blocks, threads, 0, stream>>>(dst, deg, rank, E);
            scan_k1<<<NBB, 256, 0, stream>>>(deg, bsum, N);
            scan_k2<<<1, 1024, 0, stream>>>(bsum, boff, NBB);
            scan_k3<<<NBB, 256, 0, stream>>>(deg, boff, row_ptr, N);
            perm_rank_kernel<<<blocks, threads, 0, stream>>>(src, dst, rank, row_ptr,
                                                             sorted_src, E);
        }
        {
            int total = N * D;
            int nthr = (total + 3) / 4;
            convert_kernel<<<(nthr + 255) / 256, 256, 0, stream>>>(x0, Xb, total);
        }

        const int gather_blocks = (N + 3) / 4;   // one wave per node
        const int dense_blocks = 1024;

        // agg lives in d_out every layer; activations ping in-place in Xb.
        for (int layer = 0; layer < n_layers; ++layer) {
            gather_bf16<<<gather_blocks, 256, 0, stream>>>(Xb, row_ptr, sorted_src, out, N);
            dense_bf16<<<dense_blocks, 256, 0, stream>>>(
                Xb, out,
                Wself + (size_t)layer * D * D,
                Wmsg  + (size_t)layer * D * D,
                bias  + (size_t)layer * D,
                out, Xb, N, (layer == n_layers - 1) ? 1 : 0);
        }
    } else {
        // fallback: fp32 atomic path
        float* agg = (float*)d_ws;
        const int EPB = 256 / 64;
        const int scatter_blocks = (E + EPB - 1) / EPB;
        for (int layer = 0; layer < n_layers; ++layer) {
            hipMemsetAsync(agg, 0, NB, stream);
            const float* xin = (layer == 0) ? x0 : out;
            scatter_kernel<<<scatter_blocks, 256, 0, stream>>>(xin, src, dst, agg, E);
            dense_kernel<<<1024, 256, 0, stream>>>(
                xin, agg,
                Wself + (size_t)layer * D * D,
                Wmsg  + (size_t)layer * D * D,
                bias  + (size_t)layer * D,
                out, N, (layer < n_layers - 1) ? 1 : 0);
        }
    }
}

// Round 7
// 327.183 us; speedup vs baseline: 1.3592x; 1.0384x over previous
//
#include <hip/hip_runtime.h>

#define D 64

// ---- bf16 helpers (RNE), raw ushort storage ------------------------------
__device__ __forceinline__ unsigned short f2bf(float f) {
    unsigned u = __float_as_uint(f);
    unsigned r = (u + 0x7FFFu + ((u >> 16) & 1u)) >> 16;
    return (unsigned short)r;
}
__device__ __forceinline__ float bf2f(unsigned short h) {
    return __uint_as_float((unsigned)h << 16);
}
__device__ __forceinline__ float bcast(float v, int lane_lit) {
    return __int_as_float(__builtin_amdgcn_readlane(__float_as_int(v), lane_lit));
}

// ================= CSR build: hist captures per-edge rank ===================
__global__ void hist_rank_kernel(const int* __restrict__ dst, int* __restrict__ deg,
                                 int* __restrict__ rank, int E) {
    int i = blockIdx.x * blockDim.x + threadIdx.x;
    int base = i * 8;
    if (base + 8 <= E) {
        int4 d0 = *reinterpret_cast<const int4*>(dst + base);
        int4 d1 = *reinterpret_cast<const int4*>(dst + base + 4);
        int4 r0, r1;                       // 8 independent atomic chains
        r0.x = atomicAdd(&deg[d0.x], 1);
        r0.y = atomicAdd(&deg[d0.y], 1);
        r0.z = atomicAdd(&deg[d0.z], 1);
        r0.w = atomicAdd(&deg[d0.w], 1);
        r1.x = atomicAdd(&deg[d1.x], 1);
        r1.y = atomicAdd(&deg[d1.y], 1);
        r1.z = atomicAdd(&deg[d1.z], 1);
        r1.w = atomicAdd(&deg[d1.w], 1);
        *reinterpret_cast<int4*>(rank + base) = r0;       // contiguous stream
        *reinterpret_cast<int4*>(rank + base + 4) = r1;
    } else {
        for (int e = base; e < E; ++e) rank[e] = atomicAdd(&deg[dst[e]], 1);
    }
}

__global__ void scan_k1(const int* __restrict__ deg, int* __restrict__ bsum, int n) {
    __shared__ int sh[256];
    int t = threadIdx.x;
    int g = blockIdx.x * 256 + t;
    int v = (g < n) ? deg[g] : 0;
    sh[t] = v;
    __syncthreads();
    for (int off = 1; off < 256; off <<= 1) {
        int u = (t >= off) ? sh[t - off] : 0;
        __syncthreads();
        sh[t] += u;
        __syncthreads();
    }
    if (t == 255) bsum[blockIdx.x] = sh[255];
}

__global__ void scan_k2(const int* __restrict__ bsum, int* __restrict__ boff, int nb) {
    __shared__ int sh[1024];
    int t = threadIdx.x;
    int v = (t < nb) ? bsum[t] : 0;
    sh[t] = v;
    __syncthreads();
    for (int off = 1; off < 1024; off <<= 1) {
        int u = (t >= off) ? sh[t - off] : 0;
        __syncthreads();
        sh[t] += u;
        __syncthreads();
    }
    if (t < nb) boff[t] = sh[t] - v;
}

__global__ void scan_k3(const int* __restrict__ deg, const int* __restrict__ boff,
                        int* __restrict__ row_ptr, int n) {
    __shared__ int sh[256];
    int t = threadIdx.x;
    int g = blockIdx.x * 256 + t;
    int v = (g < n) ? deg[g] : 0;
    sh[t] = v;
    __syncthreads();
    for (int off = 1; off < 256; off <<= 1) {
        int u = (t >= off) ? sh[t - off] : 0;
        __syncthreads();
        sh[t] += u;
        __syncthreads();
    }
    if (g < n) {
        int excl = sh[t] - v + boff[blockIdx.x];
        row_ptr[g] = excl;
        if (g == n - 1) row_ptr[n] = excl + v;
    }
}

// atomic-free permutation: pos = row_ptr[dst] + rank
__global__ void perm_rank_kernel(const int* __restrict__ src, const int* __restrict__ dst,
                                 const int* __restrict__ rank, const int* __restrict__ row_ptr,
                                 int* __restrict__ sorted_src, int E) {
    int i = blockIdx.x * blockDim.x + threadIdx.x;
    int base = i * 8;
    if (base + 8 <= E) {
        int4 d0 = *reinterpret_cast<const int4*>(dst + base);
        int4 d1 = *reinterpret_cast<const int4*>(dst + base + 4);
        int4 s0 = *reinterpret_cast<const int4*>(src + base);
        int4 s1 = *reinterpret_cast<const int4*>(src + base + 4);
        int4 r0 = *reinterpret_cast<const int4*>(rank + base);
        int4 r1 = *reinterpret_cast<const int4*>(rank + base + 4);
        int p0 = row_ptr[d0.x] + r0.x;
        int p1 = row_ptr[d0.y] + r0.y;
        int p2 = row_ptr[d0.z] + r0.z;
        int p3 = row_ptr[d0.w] + r0.w;
        int p4 = row_ptr[d1.x] + r1.x;
        int p5 = row_ptr[d1.y] + r1.y;
        int p6 = row_ptr[d1.z] + r1.z;
        int p7 = row_ptr[d1.w] + r1.w;
        __builtin_nontemporal_store(s0.x, &sorted_src[p0]);
        __builtin_nontemporal_store(s0.y, &sorted_src[p1]);
        __builtin_nontemporal_store(s0.z, &sorted_src[p2]);
        __builtin_nontemporal_store(s0.w, &sorted_src[p3]);
        __builtin_nontemporal_store(s1.x, &sorted_src[p4]);
        __builtin_nontemporal_store(s1.y, &sorted_src[p5]);
        __builtin_nontemporal_store(s1.z, &sorted_src[p6]);
        __builtin_nontemporal_store(s1.w, &sorted_src[p7]);
    } else {
        for (int e = base; e < E; ++e)
            sorted_src[row_ptr[dst[e]] + rank[e]] = src[e];
    }
}

// ================= x (fp32) -> Xb (bf16) ====================================
__global__ void convert_kernel(const float* __restrict__ x, unsigned short* __restrict__ xb,
                               int total) {
    int i = blockIdx.x * blockDim.x + threadIdx.x;
    int base = i * 4;
    if (base + 4 <= total) {
        float4 v = *reinterpret_cast<const float4*>(x + base);
        ushort4 o;
        o.x = f2bf(v.x); o.y = f2bf(v.y); o.z = f2bf(v.z); o.w = f2bf(v.w);
        *reinterpret_cast<ushort4*>(xb + base) = o;
    } else {
        for (int k = base; k < total; ++k) xb[k] = f2bf(x[k]);
    }
}

// ====== gather v2: 4 groups x 16 lanes; one wave-instr = 4 edges x 128B =====
// agg[n] = sum_{e in row n} bf16row(xb[src_e])   (fp32 accumulate)
__global__ void __launch_bounds__(256)
gather_bf16(const unsigned short* __restrict__ xb,
            const int* __restrict__ row_ptr,
            const int* __restrict__ sorted_src,
            float* __restrict__ agg, int n_nodes) {
    int lane = threadIdx.x & 63;
    int n = blockIdx.x * (blockDim.x >> 6) + (threadIdx.x >> 6);
    if (n >= n_nodes) return;
    int g = lane >> 4;          // edge slot within a step
    int j = lane & 15;          // feature-quad index (features 4j..4j+3)

    int beg = row_ptr[n];
    int end = row_ptr[n + 1];

    float ax0 = 0.f, ay0 = 0.f, az0 = 0.f, aw0 = 0.f;
    float ax1 = 0.f, ay1 = 0.f, az1 = 0.f, aw1 = 0.f;

    int e = beg + g;
    // ILP-2: two edges in flight per group (8 edges per wave iteration)
    for (; e + 4 < end; e += 8) {
        int s0 = sorted_src[e];          // lanes of a group share the address;
        int s1 = sorted_src[e + 4];      // groups cover a contiguous 16B run
        uint2 u0 = *reinterpret_cast<const uint2*>(xb + (((size_t)(unsigned)s0) << 6) + (j << 2));
        uint2 u1 = *reinterpret_cast<const uint2*>(xb + (((size_t)(unsigned)s1) << 6) + (j << 2));
        ax0 += __uint_as_float(u0.x << 16);
        ay0 += __uint_as_float(u0.x & 0xFFFF0000u);
        az0 += __uint_as_float(u0.y << 16);
        aw0 += __uint_as_float(u0.y & 0xFFFF0000u);
        ax1 += __uint_as_float(u1.x << 16);
        ay1 += __uint_as_float(u1.x & 0xFFFF0000u);
        az1 += __uint_as_float(u1.y << 16);
        aw1 += __uint_as_float(u1.y & 0xFFFF0000u);
    }
    for (; e < end; e += 4) {
        int s0 = sorted_src[e];
        uint2 u0 = *reinterpret_cast<const uint2*>(xb + (((size_t)(unsigned)s0) << 6) + (j << 2));
        ax0 += __uint_as_float(u0.x << 16);
        ay0 += __uint_as_float(u0.x & 0xFFFF0000u);
        az0 += __uint_as_float(u0.y << 16);
        aw0 += __uint_as_float(u0.y & 0xFFFF0000u);
    }
    ax0 += ax1; ay0 += ay1; az0 += az1; aw0 += aw1;
    // combine the 4 groups (butterfly over lane bits 4,5)
    ax0 += __shfl_xor(ax0, 16); ay0 += __shfl_xor(ay0, 16);
    az0 += __shfl_xor(az0, 16); aw0 += __shfl_xor(aw0, 16);
    ax0 += __shfl_xor(ax0, 32); ay0 += __shfl_xor(ay0, 32);
    az0 += __shfl_xor(az0, 32); aw0 += __shfl_xor(aw0, 32);

    if (g == 0) {
        float4 r;
        r.x = ax0; r.y = ay0; r.z = az0; r.w = aw0;
        *reinterpret_cast<float4*>(agg + (((size_t)(unsigned)n) << 6) + (j << 2)) = r;
    }
}

// ====== dense: y[n] = xb[n]@Ws + agg[n]@Wm + b; mode: bf16+relu or fp32 =====
// In-place safe (each wave reads only its own row before writing it).
__global__ void __launch_bounds__(256)
dense_bf16(const unsigned short* __restrict__ xb,
           const float* __restrict__ agg,
           const float* __restrict__ Wself,
           const float* __restrict__ Wmsg,
           const float* __restrict__ bias,
           float* __restrict__ out_f32,            // used when last==1
           unsigned short* __restrict__ out_bf16,  // used when last==0 (+relu)
           int n_nodes, int last) {
    int lane = threadIdx.x & 63;
    int wave = threadIdx.x >> 6;
    int wpb = blockDim.x >> 6;

    float Wsc[D], Wmc[D];
#pragma unroll
    for (int k = 0; k < D; ++k) {
        Wsc[k] = Wself[k * D + lane];
        Wmc[k] = Wmsg[k * D + lane];
    }
    float bj = bias[lane];

    for (int n = blockIdx.x * wpb + wave; n < n_nodes; n += gridDim.x * wpb) {
        float xv = bf2f(xb[((unsigned)n << 6) + lane]);
        float av = agg[((unsigned)n << 6) + lane];

        float acc0 = bj, acc1 = 0.f, acc2 = 0.f, acc3 = 0.f;
#pragma unroll
        for (int k = 0; k < D; k += 4) {
            acc0 = fmaf(bcast(xv, k + 0), Wsc[k + 0], acc0);
            acc1 = fmaf(bcast(xv, k + 1), Wsc[k + 1], acc1);
            acc2 = fmaf(bcast(xv, k + 2), Wsc[k + 2], acc2);
            acc3 = fmaf(bcast(xv, k + 3), Wsc[k + 3], acc3);
            acc0 = fmaf(bcast(av, k + 0), Wmc[k + 0], acc0);
            acc1 = fmaf(bcast(av, k + 1), Wmc[k + 1], acc1);
            acc2 = fmaf(bcast(av, k + 2), Wmc[k + 2], acc2);
            acc3 = fmaf(bcast(av, k + 3), Wmc[k + 3], acc3);
        }
        float acc = (acc0 + acc1) + (acc2 + acc3);
        if (last) {
            out_f32[((unsigned)n << 6) + lane] = acc;
        } else {
            out_bf16[((unsigned)n << 6) + lane] = f2bf(fmaxf(acc, 0.f));
        }
    }
}

// ================= fallback (atomic path, fp32-exact) =======================
__global__ void scatter_kernel(const float* __restrict__ x,
                               const int* __restrict__ src,
                               const int* __restrict__ dst,
                               float* __restrict__ agg, int n_edges) {
    int e = blockIdx.x * (blockDim.x >> 6) + (threadIdx.x >> 6);
    int lane = threadIdx.x & 63;
    if (e >= n_edges) return;
    float v = x[(size_t)src[e] * D + lane];
    unsafeAtomicAdd(&agg[(size_t)dst[e] * D + lane], v);
}

__global__ void dense_kernel(const float* __restrict__ xin,
                             const float* __restrict__ agg,
                             const float* __restrict__ Wself,
                             const float* __restrict__ Wmsg,
                             const float* __restrict__ bias,
                             float* __restrict__ xout,
                             int n_nodes, int do_relu) {
    __shared__ float Ws[D * D];
    __shared__ float Wm[D * D];
    for (int i = threadIdx.x; i < D * D; i += blockDim.x) {
        Ws[i] = Wself[i];
        Wm[i] = Wmsg[i];
    }
    __syncthreads();
    int lane = threadIdx.x & 63;
    int wave = threadIdx.x >> 6;
    int wpb = blockDim.x >> 6;
    float bj = bias[lane];
    for (int n = blockIdx.x * wpb + wave; n < n_nodes; n += gridDim.x * wpb) {
        float xv = xin[(size_t)n * D + lane];
        float av = agg[(size_t)n * D + lane];
        float acc = bj;
#pragma unroll
        for (int k = 0; k < D; ++k) {
            acc += __shfl(xv, k, 64) * Ws[k * D + lane]
                 + __shfl(av, k, 64) * Wm[k * D + lane];
        }
        if (do_relu) acc = fmaxf(acc, 0.f);
        xout[(size_t)n * D + lane] = acc;
    }
}

// ============================================================================
extern "C" void kernel_launch(void* const* d_in, const int* in_sizes, int n_in,
                              void* d_out, int out_size, void* d_ws, size_t ws_size,
                              hipStream_t stream) {
    const float* x0    = (const float*)d_in[0];
    const int*   ei    = (const int*)d_in[1];
    const float* Wmsg  = (const float*)d_in[2];
    const float* Wself = (const float*)d_in[3];
    const float* bias  = (const float*)d_in[4];
    float* out = (float*)d_out;

    const int N = in_sizes[0] / D;         // 50000
    const int E = in_sizes[1] / 2;         // 800000
    const int n_layers = in_sizes[4] / D;  // 3

    const int* src = ei;
    const int* dst = ei + E;
    const size_t NB = (size_t)N * D * sizeof(float);

    const int NBB = (N + 255) / 256;
    const size_t need = (size_t)N * D * 2          // Xb (bf16 activations)
                      + (size_t)E * 4              // sorted_src
                      + (size_t)E * 4              // rank
                      + (size_t)(N + 1) * 4        // row_ptr
                      + (size_t)N * 4              // deg
                      + (size_t)NBB * 4 * 2 + 256; // bsum + boff + slack

    if (ws_size >= need && NBB <= 1024) {
        char* p = (char*)d_ws;
        unsigned short* Xb = (unsigned short*)p;  p += (size_t)N * D * 2;
        int* sorted_src    = (int*)p;             p += (size_t)E * 4;
        int* rank          = (int*)p;             p += (size_t)E * 4;
        int* row_ptr       = (int*)p;             p += (size_t)(N + 1) * 4;
        int* deg           = (int*)p;             p += (size_t)N * 4;
        int* bsum          = (int*)p;             p += (size_t)NBB * 4;
        int* boff          = (int*)p;

        hipMemsetAsync(deg, 0, (size_t)N * 4, stream);
        {
            int threads = 256;
            int nthr = (E + 7) / 8;
            int blocks = (nthr + threads - 1) / threads;
            hist_rank_kernel<<<blocks, threads, 0, stream>>>(dst, deg, rank, E);
            scan_k1<<<NBB, 256, 0, stream>>>(deg, bsum, N);
            scan_k2<<<1, 1024, 0, stream>>>(bsum, boff, NBB);
            scan_k3<<<NBB, 256, 0, stream>>>(deg, boff, row_ptr, N);
            perm_rank_kernel<<<blocks, threads, 0, stream>>>(src, dst, rank, row_ptr,
                                                             sorted_src, E);
        }
        {
            int total = N * D;
            int nthr = (total + 3) / 4;
            convert_kernel<<<(nthr + 255) / 256, 256, 0, stream>>>(x0, Xb, total);
        }

        const int gather_blocks = (N + 3) / 4;   // one wave per node
        const int dense_blocks = 1024;

        // agg lives in d_out every layer; activations ping in-place in Xb.
        for (int layer = 0; layer < n_layers; ++layer) {
            gather_bf16<<<gather_blocks, 256, 0, stream>>>(Xb, row_ptr, sorted_src, out, N);
            dense_bf16<<<dense_blocks, 256, 0, stream>>>(
                Xb, out,
                Wself + (size_t)layer * D * D,
                Wmsg  + (size_t)layer * D * D,
                bias  + (size_t)layer * D,
                out, Xb, N, (layer == n_layers - 1) ? 1 : 0);
        }
    } else {
        // fallback: fp32 atomic path
        float* agg = (float*)d_ws;
        const int EPB = 256 / 64;
        const int scatter_blocks = (E + EPB - 1) / EPB;
        for (int layer = 0; layer < n_layers; ++layer) {
            hipMemsetAsync(agg, 0, NB, stream);
            const float* xin = (layer == 0) ? x0 : out;
            scatter_kernel<<<scatter_blocks, 256, 0, stream>>>(xin, src, dst, agg, E);
            dense_kernel<<<1024, 256, 0, stream>>>(
                xin, agg,
                Wself + (size_t)layer * D * D,
                Wmsg  + (size_t)layer * D * D,
                bias  + (size_t)layer * D,
                out, N, (layer < n_layers - 1) ? 1 : 0);
        }
    }
}

// Round 8
// 325.098 us; speedup vs baseline: 1.3679x; 1.0064x over previous
//
#include <hip/hip_runtime.h>

#define D 64

// ---- bf16 helpers (RNE), raw ushort storage ------------------------------
__device__ __forceinline__ unsigned short f2bf(float f) {
    unsigned u = __float_as_uint(f);
    unsigned r = (u + 0x7FFFu + ((u >> 16) & 1u)) >> 16;
    return (unsigned short)r;
}
__device__ __forceinline__ float bf2f(unsigned short h) {
    return __uint_as_float((unsigned)h << 16);
}

// ================= CSR build: hist captures per-edge rank ===================
__global__ void hist_rank_kernel(const int* __restrict__ dst, int* __restrict__ deg,
                                 int* __restrict__ rank, int E) {
    int i = blockIdx.x * blockDim.x + threadIdx.x;
    int base = i * 8;
    if (base + 8 <= E) {
        int4 d0 = *reinterpret_cast<const int4*>(dst + base);
        int4 d1 = *reinterpret_cast<const int4*>(dst + base + 4);
        int4 r0, r1;                       // 8 independent atomic chains
        r0.x = atomicAdd(&deg[d0.x], 1);
        r0.y = atomicAdd(&deg[d0.y], 1);
        r0.z = atomicAdd(&deg[d0.z], 1);
        r0.w = atomicAdd(&deg[d0.w], 1);
        r1.x = atomicAdd(&deg[d1.x], 1);
        r1.y = atomicAdd(&deg[d1.y], 1);
        r1.z = atomicAdd(&deg[d1.z], 1);
        r1.w = atomicAdd(&deg[d1.w], 1);
        *reinterpret_cast<int4*>(rank + base) = r0;
        *reinterpret_cast<int4*>(rank + base + 4) = r1;
    } else {
        for (int e = base; e < E; ++e) rank[e] = atomicAdd(&deg[dst[e]], 1);
    }
}

__global__ void scan_k1(const int* __restrict__ deg, int* __restrict__ bsum, int n) {
    __shared__ int sh[256];
    int t = threadIdx.x;
    int g = blockIdx.x * 256 + t;
    int v = (g < n) ? deg[g] : 0;
    sh[t] = v;
    __syncthreads();
    for (int off = 1; off < 256; off <<= 1) {
        int u = (t >= off) ? sh[t - off] : 0;
        __syncthreads();
        sh[t] += u;
        __syncthreads();
    }
    if (t == 255) bsum[blockIdx.x] = sh[255];
}

__global__ void scan_k2(const int* __restrict__ bsum, int* __restrict__ boff, int nb) {
    __shared__ int sh[1024];
    int t = threadIdx.x;
    int v = (t < nb) ? bsum[t] : 0;
    sh[t] = v;
    __syncthreads();
    for (int off = 1; off < 1024; off <<= 1) {
        int u = (t >= off) ? sh[t - off] : 0;
        __syncthreads();
        sh[t] += u;
        __syncthreads();
    }
    if (t < nb) boff[t] = sh[t] - v;
}

__global__ void scan_k3(const int* __restrict__ deg, const int* __restrict__ boff,
                        int* __restrict__ row_ptr, int n) {
    __shared__ int sh[256];
    int t = threadIdx.x;
    int g = blockIdx.x * 256 + t;
    int v = (g < n) ? deg[g] : 0;
    sh[t] = v;
    __syncthreads();
    for (int off = 1; off < 256; off <<= 1) {
        int u = (t >= off) ? sh[t - off] : 0;
        __syncthreads();
        sh[t] += u;
        __syncthreads();
    }
    if (g < n) {
        int excl = sh[t] - v + boff[blockIdx.x];
        row_ptr[g] = excl;
        if (g == n - 1) row_ptr[n] = excl + v;
    }
}

// atomic-free permutation: pos = row_ptr[dst] + rank
__global__ void perm_rank_kernel(const int* __restrict__ src, const int* __restrict__ dst,
                                 const int* __restrict__ rank, const int* __restrict__ row_ptr,
                                 int* __restrict__ sorted_src, int E) {
    int i = blockIdx.x * blockDim.x + threadIdx.x;
    int base = i * 8;
    if (base + 8 <= E) {
        int4 d0 = *reinterpret_cast<const int4*>(dst + base);
        int4 d1 = *reinterpret_cast<const int4*>(dst + base + 4);
        int4 s0 = *reinterpret_cast<const int4*>(src + base);
        int4 s1 = *reinterpret_cast<const int4*>(src + base + 4);
        int4 r0 = *reinterpret_cast<const int4*>(rank + base);
        int4 r1 = *reinterpret_cast<const int4*>(rank + base + 4);
        int p0 = row_ptr[d0.x] + r0.x;
        int p1 = row_ptr[d0.y] + r0.y;
        int p2 = row_ptr[d0.z] + r0.z;
        int p3 = row_ptr[d0.w] + r0.w;
        int p4 = row_ptr[d1.x] + r1.x;
        int p5 = row_ptr[d1.y] + r1.y;
        int p6 = row_ptr[d1.z] + r1.z;
        int p7 = row_ptr[d1.w] + r1.w;
        __builtin_nontemporal_store(s0.x, &sorted_src[p0]);
        __builtin_nontemporal_store(s0.y, &sorted_src[p1]);
        __builtin_nontemporal_store(s0.z, &sorted_src[p2]);
        __builtin_nontemporal_store(s0.w, &sorted_src[p3]);
        __builtin_nontemporal_store(s1.x, &sorted_src[p4]);
        __builtin_nontemporal_store(s1.y, &sorted_src[p5]);
        __builtin_nontemporal_store(s1.z, &sorted_src[p6]);
        __builtin_nontemporal_store(s1.w, &sorted_src[p7]);
    } else {
        for (int e = base; e < E; ++e)
            sorted_src[row_ptr[dst[e]] + rank[e]] = src[e];
    }
}

// ================= x (fp32) -> Xb (bf16) ====================================
__global__ void convert_kernel(const float* __restrict__ x, unsigned short* __restrict__ xb,
                               int total) {
    int i = blockIdx.x * blockDim.x + threadIdx.x;
    int base = i * 4;
    if (base + 4 <= total) {
        float4 v = *reinterpret_cast<const float4*>(x + base);
        ushort4 o;
        o.x = f2bf(v.x); o.y = f2bf(v.y); o.z = f2bf(v.z); o.w = f2bf(v.w);
        *reinterpret_cast<ushort4*>(xb + base) = o;
    } else {
        for (int k = base; k < total; ++k) xb[k] = f2bf(x[k]);
    }
}

// ====== gather v3: 4 groups x 16 lanes, ILP-4 (16 rows in flight/wave) ======
// aggb[n] (bf16) = sum_{e in row n} bf16row(xb[src_e])  (fp32 accumulate)
__global__ void __launch_bounds__(256)
gather_bf16(const unsigned short* __restrict__ xb,
            const int* __restrict__ row_ptr,
            const int* __restrict__ sorted_src,
            unsigned short* __restrict__ aggb, int n_nodes) {
    int lane = threadIdx.x & 63;
    int n = blockIdx.x * (blockDim.x >> 6) + (threadIdx.x >> 6);
    if (n >= n_nodes) return;
    int g = lane >> 4;          // edge slot within a 4-edge step
    int j = lane & 15;          // feature-quad index (features 4j..4j+3)

    int beg = row_ptr[n];
    int end = row_ptr[n + 1];

    float ax0=0.f, ay0=0.f, az0=0.f, aw0=0.f;
    float ax1=0.f, ay1=0.f, az1=0.f, aw1=0.f;
    float ax2=0.f, ay2=0.f, az2=0.f, aw2=0.f;
    float ax3=0.f, ay3=0.f, az3=0.f, aw3=0.f;

    int e = beg + g;
    for (; e + 12 < end; e += 16) {           // ILP-4 per group
        int s0 = sorted_src[e];
        int s1 = sorted_src[e + 4];
        int s2 = sorted_src[e + 8];
        int s3 = sorted_src[e + 12];
        uint2 u0 = *reinterpret_cast<const uint2*>(xb + (((size_t)(unsigned)s0) << 6) + (j << 2));
        uint2 u1 = *reinterpret_cast<const uint2*>(xb + (((size_t)(unsigned)s1) << 6) + (j << 2));
        uint2 u2 = *reinterpret_cast<const uint2*>(xb + (((size_t)(unsigned)s2) << 6) + (j << 2));
        uint2 u3 = *reinterpret_cast<const uint2*>(xb + (((size_t)(unsigned)s3) << 6) + (j << 2));
        ax0 += __uint_as_float(u0.x << 16); ay0 += __uint_as_float(u0.x & 0xFFFF0000u);
        az0 += __uint_as_float(u0.y << 16); aw0 += __uint_as_float(u0.y & 0xFFFF0000u);
        ax1 += __uint_as_float(u1.x << 16); ay1 += __uint_as_float(u1.x & 0xFFFF0000u);
        az1 += __uint_as_float(u1.y << 16); aw1 += __uint_as_float(u1.y & 0xFFFF0000u);
        ax2 += __uint_as_float(u2.x << 16); ay2 += __uint_as_float(u2.x & 0xFFFF0000u);
        az2 += __uint_as_float(u2.y << 16); aw2 += __uint_as_float(u2.y & 0xFFFF0000u);
        ax3 += __uint_as_float(u3.x << 16); ay3 += __uint_as_float(u3.x & 0xFFFF0000u);
        az3 += __uint_as_float(u3.y << 16); aw3 += __uint_as_float(u3.y & 0xFFFF0000u);
    }
    for (; e < end; e += 4) {
        int s0 = sorted_src[e];
        uint2 u0 = *reinterpret_cast<const uint2*>(xb + (((size_t)(unsigned)s0) << 6) + (j << 2));
        ax0 += __uint_as_float(u0.x << 16); ay0 += __uint_as_float(u0.x & 0xFFFF0000u);
        az0 += __uint_as_float(u0.y << 16); aw0 += __uint_as_float(u0.y & 0xFFFF0000u);
    }
    float ax = (ax0 + ax1) + (ax2 + ax3);
    float ay = (ay0 + ay1) + (ay2 + ay3);
    float az = (az0 + az1) + (az2 + az3);
    float aw = (aw0 + aw1) + (aw2 + aw3);
    // combine the 4 groups (butterfly over lane bits 4,5)
    ax += __shfl_xor(ax, 16); ay += __shfl_xor(ay, 16);
    az += __shfl_xor(az, 16); aw += __shfl_xor(aw, 16);
    ax += __shfl_xor(ax, 32); ay += __shfl_xor(ay, 32);
    az += __shfl_xor(az, 32); aw += __shfl_xor(aw, 32);

    if (g == 0) {
        uint2 o;
        o.x = (unsigned)f2bf(ax) | ((unsigned)f2bf(ay) << 16);
        o.y = (unsigned)f2bf(az) | ((unsigned)f2bf(aw) << 16);
        *reinterpret_cast<uint2*>(aggb + (((size_t)(unsigned)n) << 6) + (j << 2)) = o;
    }
}

// ====== dense v3: SGPR-broadcast rows + SALU bf16 unpack ====================
// y[n] = xb[n]@Ws + aggb[n]@Wm + b ; intermediate: bf16+relu -> out_bf16,
// last: fp32 -> out_f32. Row address is wave-uniform -> scalar loads.
__global__ void __launch_bounds__(256)
dense_v3(const unsigned short* __restrict__ xb,
         const unsigned short* __restrict__ aggb,
         const float* __restrict__ Wself,
         const float* __restrict__ Wmsg,
         const float* __restrict__ bias,
         float* __restrict__ out_f32,
         unsigned short* __restrict__ out_bf16,
         int n_nodes, int last) {
    int lane = threadIdx.x & 63;
    int wave = threadIdx.x >> 6;
    int wpb = blockDim.x >> 6;

    float Wsc[D], Wmc[D];          // column `lane` of each W, fp32, in VGPRs
#pragma unroll
    for (int k = 0; k < D; ++k) {
        Wsc[k] = Wself[k * D + lane];
        Wmc[k] = Wmsg[k * D + lane];
    }
    float bj = bias[lane];

    for (int n0 = blockIdx.x * wpb + wave; n0 < n_nodes; n0 += gridDim.x * wpb) {
        int n = __builtin_amdgcn_readfirstlane(n0);   // force wave-uniform/SGPR
        const unsigned* xrow = reinterpret_cast<const unsigned*>(xb)   + ((size_t)(unsigned)n << 5);
        const unsigned* arow = reinterpret_cast<const unsigned*>(aggb) + ((size_t)(unsigned)n << 5);

        float acc0 = bj, acc1 = 0.f, acc2 = 0.f, acc3 = 0.f;
#pragma unroll
        for (int dq = 0; dq < 32; dq += 2) {          // 2 dwords = 4 features
            unsigned xu0 = xrow[dq], xu1 = xrow[dq + 1];
            unsigned au0 = arow[dq], au1 = arow[dq + 1];
            acc0 = fmaf(__uint_as_float(xu0 << 16),         Wsc[2 * dq + 0], acc0);
            acc1 = fmaf(__uint_as_float(xu0 & 0xFFFF0000u), Wsc[2 * dq + 1], acc1);
            acc2 = fmaf(__uint_as_float(xu1 << 16),         Wsc[2 * dq + 2], acc2);
            acc3 = fmaf(__uint_as_float(xu1 & 0xFFFF0000u), Wsc[2 * dq + 3], acc3);
            acc0 = fmaf(__uint_as_float(au0 << 16),         Wmc[2 * dq + 0], acc0);
            acc1 = fmaf(__uint_as_float(au0 & 0xFFFF0000u), Wmc[2 * dq + 1], acc1);
            acc2 = fmaf(__uint_as_float(au1 << 16),         Wmc[2 * dq + 2], acc2);
            acc3 = fmaf(__uint_as_float(au1 & 0xFFFF0000u), Wmc[2 * dq + 3], acc3);
        }
        float acc = (acc0 + acc1) + (acc2 + acc3);
        if (last) {
            out_f32[((size_t)(unsigned)n << 6) + lane] = acc;
        } else {
            out_bf16[((size_t)(unsigned)n << 6) + lane] = f2bf(fmaxf(acc, 0.f));
        }
    }
}

// ================= fallback (atomic path, fp32-exact) =======================
__global__ void scatter_kernel(const float* __restrict__ x,
                               const int* __restrict__ src,
                               const int* __restrict__ dst,
                               float* __restrict__ agg, int n_edges) {
    int e = blockIdx.x * (blockDim.x >> 6) + (threadIdx.x >> 6);
    int lane = threadIdx.x & 63;
    if (e >= n_edges) return;
    float v = x[(size_t)src[e] * D + lane];
    unsafeAtomicAdd(&agg[(size_t)dst[e] * D + lane], v);
}

__global__ void dense_kernel(const float* __restrict__ xin,
                             const float* __restrict__ agg,
                             const float* __restrict__ Wself,
                             const float* __restrict__ Wmsg,
                             const float* __restrict__ bias,
                             float* __restrict__ xout,
                             int n_nodes, int do_relu) {
    __shared__ float Ws[D * D];
    __shared__ float Wm[D * D];
    for (int i = threadIdx.x; i < D * D; i += blockDim.x) {
        Ws[i] = Wself[i];
        Wm[i] = Wmsg[i];
    }
    __syncthreads();
    int lane = threadIdx.x & 63;
    int wave = threadIdx.x >> 6;
    int wpb = blockDim.x >> 6;
    float bj = bias[lane];
    for (int n = blockIdx.x * wpb + wave; n < n_nodes; n += gridDim.x * wpb) {
        float xv = xin[(size_t)n * D + lane];
        float av = agg[(size_t)n * D + lane];
        float acc = bj;
#pragma unroll
        for (int k = 0; k < D; ++k) {
            acc += __shfl(xv, k, 64) * Ws[k * D + lane]
                 + __shfl(av, k, 64) * Wm[k * D + lane];
        }
        if (do_relu) acc = fmaxf(acc, 0.f);
        xout[(size_t)n * D + lane] = acc;
    }
}

// ============================================================================
extern "C" void kernel_launch(void* const* d_in, const int* in_sizes, int n_in,
                              void* d_out, int out_size, void* d_ws, size_t ws_size,
                              hipStream_t stream) {
    const float* x0    = (const float*)d_in[0];
    const int*   ei    = (const int*)d_in[1];
    const float* Wmsg  = (const float*)d_in[2];
    const float* Wself = (const float*)d_in[3];
    const float* bias  = (const float*)d_in[4];
    float* out = (float*)d_out;

    const int N = in_sizes[0] / D;         // 50000
    const int E = in_sizes[1] / 2;         // 800000
    const int n_layers = in_sizes[4] / D;  // 3

    const int* src = ei;
    const int* dst = ei + E;
    const size_t NB = (size_t)N * D * sizeof(float);

    const int NBB = (N + 255) / 256;
    const size_t need = (size_t)N * D * 2          // Xb (bf16 activations)
                      + (size_t)N * D * 2          // aggb (bf16 aggregate)
                      + (size_t)E * 4              // sorted_src
                      + (size_t)E * 4              // rank
                      + (size_t)(N + 1) * 4        // row_ptr
                      + (size_t)N * 4              // deg
                      + (size_t)NBB * 4 * 2 + 256; // bsum + boff + slack

    if (ws_size >= need && NBB <= 1024) {
        char* p = (char*)d_ws;
        unsigned short* Xb   = (unsigned short*)p;  p += (size_t)N * D * 2;
        unsigned short* Aggb = (unsigned short*)p;  p += (size_t)N * D * 2;
        int* sorted_src      = (int*)p;             p += (size_t)E * 4;
        int* rank            = (int*)p;             p += (size_t)E * 4;
        int* row_ptr         = (int*)p;             p += (size_t)(N + 1) * 4;
        int* deg             = (int*)p;             p += (size_t)N * 4;
        int* bsum            = (int*)p;             p += (size_t)NBB * 4;
        int* boff            = (int*)p;

        hipMemsetAsync(deg, 0, (size_t)N * 4, stream);
        {
            int threads = 256;
            int nthr = (E + 7) / 8;
            int blocks = (nthr + threads - 1) / threads;
            hist_rank_kernel<<<blocks, threads, 0, stream>>>(dst, deg, rank, E);
            scan_k1<<<NBB, 256, 0, stream>>>(deg, bsum, N);
            scan_k2<<<1, 1024, 0, stream>>>(bsum, boff, NBB);
            scan_k3<<<NBB, 256, 0, stream>>>(deg, boff, row_ptr, N);
            perm_rank_kernel<<<blocks, threads, 0, stream>>>(src, dst, rank, row_ptr,
                                                             sorted_src, E);
        }
        {
            int total = N * D;
            int nthr = (total + 3) / 4;
            convert_kernel<<<(nthr + 255) / 256, 256, 0, stream>>>(x0, Xb, total);
        }

        const int gather_blocks = (N + 3) / 4;   // one wave per node
        const int dense_blocks = 1024;           // grid-stride, W fill amortized

        for (int layer = 0; layer < n_layers; ++layer) {
            gather_bf16<<<gather_blocks, 256, 0, stream>>>(Xb, row_ptr, sorted_src, Aggb, N);
            dense_v3<<<dense_blocks, 256, 0, stream>>>(
                Xb, Aggb,
                Wself + (size_t)layer * D * D,
                Wmsg  + (size_t)layer * D * D,
                bias  + (size_t)layer * D,
                out, Xb, N, (layer == n_layers - 1) ? 1 : 0);
        }
    } else {
        // fallback: fp32 atomic path
        float* agg = (float*)d_ws;
        const int EPB = 256 / 64;
        const int scatter_blocks = (E + EPB - 1) / EPB;
        for (int layer = 0; layer < n_layers; ++layer) {
            hipMemsetAsync(agg, 0, NB, stream);
            const float* xin = (layer == 0) ? x0 : out;
            scatter_kernel<<<scatter_blocks, 256, 0, stream>>>(xin, src, dst, agg, E);
            dense_kernel<<<1024, 256, 0, stream>>>(
                xin, agg,
                Wself + (size_t)layer * D * D,
                Wmsg  + (size_t)layer * D * D,
                bias  + (size_t)layer * D,
                out, N, (layer < n_layers - 1) ? 1 : 0);
        }
    }
}